// Round 7
// baseline (444.242 us; speedup 1.0000x reference)
//
#include <hip/hip_runtime.h>
#include <hip/hip_cooperative_groups.h>

namespace cg = cooperative_groups;

#define NEG_SLOPE 0.2f
#define BUK_SHIFT 9
#define BUK_SIZE 512
#define BUK_CAP 16384

typedef unsigned short u16;
typedef __attribute__((ext_vector_type(4))) float f4v;
typedef _Float16 h8 __attribute__((ext_vector_type(8)));  // 4 VGPRs, MFMA f16 A/B frag

struct MegaP {
    const float* x;
    const int* ei;
    const float *W1, *as1, *ad1, *b1;
    const float *W2, *as2, *ad2, *b2;
    const float *W3, *as3, *ad3, *b3;
    float* out;
    int N, E, NB, NBIN, GTOT, VB128, VB64;
    int *g_cnt, *buckets, *csr_ptr, *csr_src;
    float *als, *ald;
    _Float16* Hbuf;
    u16* XH;
    u16 *WT1h, *WT1l, *WT2h, *WT2l, *WT3h, *WT3l;
};

__device__ __forceinline__ u16 f2h_bits(_Float16 h) {
    union { _Float16 f; u16 u; } c;
    c.f = h;
    return c.u;
}

// ---------------- roles (shared by mega + fallback) ----------------

__device__ void wsplit_role(const MegaP& p, int idx) {
    // idx in [0, 40960)
    const float* W;
    u16 *Th, *Tl;
    int M, li;
    if (idx < 16384) {
        W = p.W1; Th = p.WT1h; Tl = p.WT1l; M = 128; li = idx;
    } else if (idx < 32768) {
        W = p.W2; Th = p.WT2h; Tl = p.WT2l; M = 128; li = idx - 16384;
    } else {
        W = p.W3; Th = p.WT3h; Tl = p.WT3l; M = 64; li = idx - 32768;
    }
    int c = li >> 7, k = li & 127;
    float v = W[(size_t)k * M + c];
    _Float16 h = (_Float16)v;
    _Float16 l = (_Float16)(v - (float)h);
    int ct = c >> 4, ch = k >> 5, q = (k >> 3) & 3, j = k & 7;
    size_t addr = ((size_t)ct * 4 + ch) * 512 + ((c & 15) + 16 * q) * 8 + j;
    Th[addr] = f2h_bits(h);
    Tl[addr] = f2h_bits(l);
}

__device__ void wa_role(const MegaP& p, int idx) {
    if (idx >= 6144) return;
    int layer = idx >> 11;
    int rem = idx & 2047;
    int k = rem >> 4;
    int c = rem & 15;
    const float *W, *as, *ad;
    u16 *Th, *Tl;
    int M, CT, nc;
    if (layer == 0) {
        W = p.W1; as = p.as1; ad = p.ad1; Th = p.WT1h; Tl = p.WT1l; M = 128; CT = 8; nc = 4;
    } else if (layer == 1) {
        W = p.W2; as = p.as2; ad = p.ad2; Th = p.WT2h; Tl = p.WT2l; M = 128; CT = 8; nc = 4;
    } else {
        W = p.W3; as = p.as3; ad = p.ad3; Th = p.WT3h; Tl = p.WT3l; M = 64; CT = 4; nc = 2;
    }
    float val = 0.f;
    if (c < nc) {
        int side, hh;
        if (nc == 4) { side = c >> 1; hh = c & 1; }  // 0=als_h0 1=als_h1 2=ald_h0 3=ald_h1
        else { side = c; hh = 0; }
        const float* a = side ? ad : as;
        for (int j = 0; j < 64; j++)
            val += W[(size_t)k * M + hh * 64 + j] * a[hh * 64 + j];
    }
    _Float16 h = (_Float16)val;
    _Float16 l = (_Float16)(val - (float)h);
    int ch = k >> 5, q = (k >> 3) & 3, j = k & 7;
    size_t addr = ((size_t)CT * 4 + ch) * 512 + ((size_t)(c + 16 * q)) * 8 + j;
    Th[addr] = f2h_bits(h);
    Tl[addr] = f2h_bits(l);
}

__device__ void binscatter_role(const MegaP& p, int b, int t, int* smem) {
    int* lcnt = smem;
    int* lbase = smem + 256;
    int* lcur = smem + 512;
    int nb = p.NB;
    if (t < nb) {
        lcnt[t] = 0;
        lcur[t] = 0;
    }
    __syncthreads();
    int tile0 = b * 4096;
    int pk[8], bk[8];
#pragma unroll
    for (int k = 0; k < 8; k++) {
        int idx = tile0 + k * 512 + t;
        bk[k] = -1;
        if (idx < p.E) {
            int s = p.ei[idx];
            int d = p.ei[p.E + idx];
            bk[k] = d >> BUK_SHIFT;
            pk[k] = (s << BUK_SHIFT) | (d & (BUK_SIZE - 1));
            atomicAdd(&lcnt[bk[k]], 1);
        }
    }
    __syncthreads();
    if (t < nb && lcnt[t] > 0) lbase[t] = atomicAdd(&p.g_cnt[t], lcnt[t]);
    __syncthreads();
#pragma unroll
    for (int k = 0; k < 8; k++) {
        if (bk[k] >= 0) {
            int pos = lbase[bk[k]] + atomicAdd(&lcur[bk[k]], 1);
            if (pos < BUK_CAP) p.buckets[(bk[k] << 14) + pos] = pk[k];
        }
    }
    __syncthreads();  // smem reused by next grid-stride iteration
}

__device__ void csr_role(const MegaP& p, int b, int t, int* smem) {
    int* lcnt = smem;
    int* lsc = smem + 512;
    int* lcur = smem + 1024;
    int* bsc = smem + 1536;
    int n = p.N, nb = p.NB;
    int nodes = min(BUK_SIZE, n - b * BUK_SIZE);
    int cnt = min(p.g_cnt[b], BUK_CAP);
    const int* bp = &p.buckets[b << 14];

    int bv = 0;
    if (t < nb) bv = min(p.g_cnt[t], BUK_CAP) + min(BUK_SIZE, n - t * BUK_SIZE);
    bsc[t] = bv;
    __syncthreads();
    for (int off = 1; off < 512; off <<= 1) {
        int xx = (t >= off) ? bsc[t - off] : 0;
        __syncthreads();
        bsc[t] += xx;
        __syncthreads();
    }
    int boff = bsc[b] - (cnt + nodes);
    int total = bsc[nb - 1];
    __syncthreads();

    lcnt[t] = 0;
    __syncthreads();
    for (int i = t; i < cnt; i += 512) atomicAdd(&lcnt[bp[i] & (BUK_SIZE - 1)], 1);
    __syncthreads();
    int myc = (t < nodes) ? (lcnt[t] + 1) : 0;
    lsc[t] = myc;
    __syncthreads();
    for (int off = 1; off < 512; off <<= 1) {
        int xx = (t >= off) ? lsc[t - off] : 0;
        __syncthreads();
        lsc[t] += xx;
        __syncthreads();
    }
    int excl = lsc[t] - myc;
    lcur[t] = excl;
    if (t < nodes) p.csr_ptr[b * BUK_SIZE + t] = boff + excl;
    if (b == nb - 1 && t == 0) p.csr_ptr[n] = total;
    __syncthreads();
    for (int i = t; i < cnt; i += 512) {
        int v = bp[i];
        int ld = v & (BUK_SIZE - 1);
        int pos = atomicAdd(&lcur[ld], 1);
        p.csr_src[boff + pos] = v >> BUK_SHIFT;
    }
    if (t < nodes) {
        int pos = atomicAdd(&lcur[t], 1);
        p.csr_src[boff + pos] = b * BUK_SIZE + t;
    }
    __syncthreads();  // smem reused by next grid-stride iteration
}

// ---------------- GEMM body (512 thr / 256 rows, fused logit columns) ----------------

__device__ __forceinline__ void load_split_f32(const float* __restrict__ X, int row,
                                               int koff, int N, h8& hi, h8& lo) {
    float v[8];
    if (row < N) {
        float4 a = *(const float4*)&X[(size_t)row * 128 + koff];
        float4 b = *(const float4*)&X[(size_t)row * 128 + koff + 4];
        v[0] = a.x; v[1] = a.y; v[2] = a.z; v[3] = a.w;
        v[4] = b.x; v[5] = b.y; v[6] = b.z; v[7] = b.w;
    } else {
#pragma unroll
        for (int i = 0; i < 8; i++) v[i] = 0.f;
    }
    union { h8 s; _Float16 u[8]; } H, L;
#pragma unroll
    for (int i = 0; i < 8; i++) {
        H.u[i] = (_Float16)v[i];
        L.u[i] = (_Float16)(v[i] - (float)H.u[i]);
    }
    hi = H.s;
    lo = L.s;
}

template <int M, bool FP32X>
__device__ void gemm_body(int gb, const float* __restrict__ Xf, const u16* __restrict__ XH,
                          const u16* __restrict__ WTh, const u16* __restrict__ WTl,
                          _Float16* __restrict__ Hout, float* __restrict__ als,
                          float* __restrict__ ald, int nrows) {
    const int CT = M / 16;
    const int CTX = CT + 1;
    const int H = (M == 128) ? 2 : 1;
    int tid = threadIdx.x;
    int wv = tid >> 6, lane = tid & 63;
    int q = lane >> 4, nl = lane & 15;
    int R0 = gb * 256 + wv * 32;
    int rt0 = R0 >> 4;

    f4v acc[2][CTX];
    f4v z4 = {0.f, 0.f, 0.f, 0.f};
#pragma unroll
    for (int rt = 0; rt < 2; rt++)
#pragma unroll
        for (int ct = 0; ct < CTX; ct++) acc[rt][ct] = z4;

#pragma unroll
    for (int ch = 0; ch < 4; ch++) {
        h8 ah0, al0, ah1, al1;
        if (FP32X) {
            int koff = ch * 32 + q * 8;
            load_split_f32(Xf, R0 + nl, koff, nrows, ah0, al0);
            load_split_f32(Xf, R0 + 16 + nl, koff, nrows, ah1, al1);
        } else {
            size_t a0 = ((size_t)rt0 * 4 + ch) * 512 + lane * 8;
            size_t a1 = ((size_t)(rt0 + 1) * 4 + ch) * 512 + lane * 8;
            ah0 = *(const h8*)&XH[a0];
            ah1 = *(const h8*)&XH[a1];
        }
#pragma unroll
        for (int ct = 0; ct < CTX; ct++) {
            size_t bb = ((size_t)ct * 4 + ch) * 512 + lane * 8;
            h8 bh = *(const h8*)&WTh[bb];
            h8 bl = *(const h8*)&WTl[bb];
            acc[0][ct] = __builtin_amdgcn_mfma_f32_16x16x32_f16(ah0, bh, acc[0][ct], 0, 0, 0);
            acc[0][ct] = __builtin_amdgcn_mfma_f32_16x16x32_f16(ah0, bl, acc[0][ct], 0, 0, 0);
            acc[1][ct] = __builtin_amdgcn_mfma_f32_16x16x32_f16(ah1, bh, acc[1][ct], 0, 0, 0);
            acc[1][ct] = __builtin_amdgcn_mfma_f32_16x16x32_f16(ah1, bl, acc[1][ct], 0, 0, 0);
            if (FP32X) {
                acc[0][ct] = __builtin_amdgcn_mfma_f32_16x16x32_f16(al0, bh, acc[0][ct], 0, 0, 0);
                acc[1][ct] = __builtin_amdgcn_mfma_f32_16x16x32_f16(al1, bh, acc[1][ct], 0, 0, 0);
            }
        }
    }

#pragma unroll
    for (int rt = 0; rt < 2; rt++)
#pragma unroll
        for (int ct = 0; ct < CT; ct++)
#pragma unroll
            for (int r = 0; r < 4; r++) {
                int row = R0 + rt * 16 + q * 4 + r;
                if (row < nrows) Hout[(size_t)row * M + ct * 16 + nl] = (_Float16)acc[rt][ct][r];
            }

    if (nl < 2 * H) {
#pragma unroll
        for (int rt = 0; rt < 2; rt++)
#pragma unroll
            for (int r = 0; r < 4; r++) {
                int row = R0 + rt * 16 + q * 4 + r;
                if (row < nrows) {
                    float v = acc[rt][CT][r];
                    if (H == 2) {
                        float* dstp = (nl < 2) ? als : ald;
                        dstp[(size_t)row * 2 + (nl & 1)] = v;
                    } else {
                        float* dstp = (nl == 0) ? als : ald;
                        dstp[row] = v;
                    }
                }
            }
    }
}

// ---------------- agg roles (8-deep gather batches) ----------------

__device__ void agg128_role(const MegaP& p, int t, int vb, const float* __restrict__ bias) {
    int wv = t >> 6, lane = t & 63;
    int wvg = vb * 8 + wv;
    if (wvg * 4 >= p.N) return;  // wave-uniform
    int nn = lane >> 4;   // node slot 0..3
    int gl = lane & 15;   // covers cols gl*8 .. gl*8+7
    int wid = wvg * 4 + nn;
    bool valid = wid < p.N;
    int widc = valid ? wid : (p.N - 1);
    int start = p.csr_ptr[widc];
    int deg = valid ? (p.csr_ptr[widc + 1] - start) : 0;
    int md = deg;
    md = max(md, __shfl_xor(md, 16));
    md = max(md, __shfl_xor(md, 32));
    float2 adv = *(const float2*)&p.ald[(size_t)widc * 2];
    int hsel = gl >> 3;
    int coff = gl * 8;
    float z0 = 0.f, z1 = 0.f;
    float acc[8];
#pragma unroll
    for (int c = 0; c < 8; c++) acc[c] = 0.f;

    for (int base = 0; base < md; base += 16) {
        int i = base + gl;
        int s_l = 0;
        float ex0 = 0.f, ex1 = 0.f;
        if (i < deg) {
            s_l = p.csr_src[start + i];
            float2 av = *(const float2*)&p.als[(size_t)s_l * 2];
            float e0 = av.x + adv.x;
            e0 = e0 > 0.f ? e0 : NEG_SLOPE * e0;
            ex0 = __expf(e0);
            float e1 = av.y + adv.y;
            e1 = e1 > 0.f ? e1 : NEG_SLOPE * e1;
            ex1 = __expf(e1);
        }
        z0 += ex0;
        z1 += ex1;
        int cnt = min(16, md - base);  // wave-uniform
        for (int jp = 0; jp < cnt; jp += 8) {
            int nk = min(8, cnt - jp);  // wave-uniform
            h8 hv[8];
            float w[8];
#pragma unroll
            for (int k = 0; k < 8; k++) {
                if (k < nk) {
                    int j = nn * 16 + jp + k;
                    int s = __shfl(s_l, j);
                    float w0 = __shfl(ex0, j);
                    float w1 = __shfl(ex1, j);
                    w[k] = hsel ? w1 : w0;
                    hv[k] = *(const h8*)&p.Hbuf[(size_t)s * 128 + coff];
                }
            }
#pragma unroll
            for (int k = 0; k < 8; k++) {
                if (k < nk) {
#pragma unroll
                    for (int c = 0; c < 8; c++)
                        acc[c] = fmaf(w[k], (float)hv[k][c], acc[c]);
                }
            }
        }
    }

#pragma unroll
    for (int m = 1; m <= 8; m <<= 1) {
        z0 += __shfl_xor(z0, m);
        z1 += __shfl_xor(z1, m);
    }
    if (valid) {
        float zinv = hsel ? (1.f / z1) : (1.f / z0);
        float4 b0 = *(const float4*)&bias[coff];
        float4 b1 = *(const float4*)&bias[coff + 4];
        float bb[8] = {b0.x, b0.y, b0.z, b0.w, b1.x, b1.y, b1.z, b1.w};
        union { _Float16 f[8]; h8 v; } O;
#pragma unroll
        for (int c = 0; c < 8; c++) {
            float o = fmaxf(fmaf(acc[c], zinv, bb[c]), 0.f);
            O.f[c] = (_Float16)o;
        }
        int ch = coff >> 5, qq = (coff >> 3) & 3;
        size_t tb = ((size_t)(wid >> 4) * 4 + ch) * 512 + ((size_t)((wid & 15) + 16 * qq)) * 8;
        *(h8*)&p.XH[tb] = O.v;
    }
}

__device__ void agg64_role(const MegaP& p, int t, int vb) {
    int wv = t >> 6, lane = t & 63;
    int wvg = vb * 8 + wv;
    if (wvg * 8 >= p.N) return;  // wave-uniform
    int nn = lane >> 3;  // node slot 0..7
    int gl = lane & 7;   // covers cols gl*8 .. gl*8+7
    int wid = wvg * 8 + nn;
    bool valid = wid < p.N;
    int widc = valid ? wid : (p.N - 1);
    int start = p.csr_ptr[widc];
    int deg = valid ? (p.csr_ptr[widc + 1] - start) : 0;
    int md = deg;
    md = max(md, __shfl_xor(md, 8));
    md = max(md, __shfl_xor(md, 16));
    md = max(md, __shfl_xor(md, 32));
    float ad0 = p.ald[widc];
    int coff = gl * 8;
    float z = 0.f;
    float acc[8];
#pragma unroll
    for (int c = 0; c < 8; c++) acc[c] = 0.f;

    for (int base = 0; base < md; base += 8) {
        int i = base + gl;
        int s_l = 0;
        float ex0 = 0.f;
        if (i < deg) {
            s_l = p.csr_src[start + i];
            float e = p.als[s_l] + ad0;
            e = e > 0.f ? e : NEG_SLOPE * e;
            ex0 = __expf(e);
        }
        z += ex0;
        int cnt = min(8, md - base);  // wave-uniform
        h8 hv[8];
        float w[8];
#pragma unroll
        for (int k = 0; k < 8; k++) {
            if (k < cnt) {
                int j = nn * 8 + k;
                int s = __shfl(s_l, j);
                w[k] = __shfl(ex0, j);
                hv[k] = *(const h8*)&p.Hbuf[(size_t)s * 64 + coff];
            }
        }
#pragma unroll
        for (int k = 0; k < 8; k++) {
            if (k < cnt) {
#pragma unroll
                for (int c = 0; c < 8; c++)
                    acc[c] = fmaf(w[k], (float)hv[k][c], acc[c]);
            }
        }
    }

#pragma unroll
    for (int m = 1; m <= 4; m <<= 1) z += __shfl_xor(z, m);
    if (valid) {
        float zinv = 1.f / z;
        float4 b0 = *(const float4*)&p.b3[coff];
        float4 b1 = *(const float4*)&p.b3[coff + 4];
        float4 o1, o2;
        o1.x = fmaf(acc[0], zinv, b0.x);
        o1.y = fmaf(acc[1], zinv, b0.y);
        o1.z = fmaf(acc[2], zinv, b0.z);
        o1.w = fmaf(acc[3], zinv, b0.w);
        o2.x = fmaf(acc[4], zinv, b1.x);
        o2.y = fmaf(acc[5], zinv, b1.y);
        o2.z = fmaf(acc[6], zinv, b1.z);
        o2.w = fmaf(acc[7], zinv, b1.w);
        *(float4*)&p.out[(size_t)wid * 64 + coff] = o1;
        *(float4*)&p.out[(size_t)wid * 64 + coff + 4] = o2;
    }
}

// ---------------- the mega cooperative kernel ----------------

__global__ __launch_bounds__(512, 4) void mega(MegaP p) {
    __shared__ int smem[2048];
    cg::grid_group grid = cg::this_grid();
    int t = threadIdx.x;

    // P0: zero g_cnt U wsplit U wa
    for (int vb = blockIdx.x; vb < 93; vb += gridDim.x) {
        if (vb == 0) {
            if (t < 256) p.g_cnt[t] = 0;
        } else if (vb < 81) {
            wsplit_role(p, (vb - 1) * 512 + t);
        } else {
            wa_role(p, (vb - 81) * 512 + t);
        }
    }
    __threadfence();
    grid.sync();
    // P1: binscatter
    for (int vb = blockIdx.x; vb < p.NBIN; vb += gridDim.x) binscatter_role(p, vb, t, smem);
    __threadfence();
    grid.sync();
    // P2: csr U gemm layer-1
    for (int vb = blockIdx.x; vb < p.NB + p.GTOT; vb += gridDim.x) {
        if (vb < p.NB)
            csr_role(p, vb, t, smem);
        else
            gemm_body<128, true>(vb - p.NB, p.x, nullptr, p.WT1h, p.WT1l, p.Hbuf, p.als,
                                 p.ald, p.N);
    }
    __threadfence();
    grid.sync();
    // P3: agg128 layer-1
    for (int vb = blockIdx.x; vb < p.VB128; vb += gridDim.x) agg128_role(p, t, vb, p.b1);
    __threadfence();
    grid.sync();
    // P4: gemm layer-2
    for (int vb = blockIdx.x; vb < p.GTOT; vb += gridDim.x)
        gemm_body<128, false>(vb, nullptr, p.XH, p.WT2h, p.WT2l, p.Hbuf, p.als, p.ald, p.N);
    __threadfence();
    grid.sync();
    // P5: agg128 layer-2
    for (int vb = blockIdx.x; vb < p.VB128; vb += gridDim.x) agg128_role(p, t, vb, p.b2);
    __threadfence();
    grid.sync();
    // P6: gemm layer-3 (M=64)
    for (int vb = blockIdx.x; vb < p.GTOT; vb += gridDim.x)
        gemm_body<64, false>(vb, nullptr, p.XH, p.WT3h, p.WT3l, p.Hbuf, p.als, p.ald, p.N);
    __threadfence();
    grid.sync();
    // P7: agg64 (final output)
    for (int vb = blockIdx.x; vb < p.VB64; vb += gridDim.x) agg64_role(p, t, vb);
}

// ---------------- fallback kernels (plain dispatch chain) ----------------

__launch_bounds__(512) __global__ void k_f0(MegaP p) {
    int vb = blockIdx.x, t = threadIdx.x;
    if (vb == 0) {
        if (t < 256) p.g_cnt[t] = 0;
    } else if (vb < 81) {
        wsplit_role(p, (vb - 1) * 512 + t);
    } else {
        wa_role(p, (vb - 81) * 512 + t);
    }
}
__launch_bounds__(512) __global__ void k_f1(MegaP p) {
    __shared__ int smem[2048];
    binscatter_role(p, blockIdx.x, threadIdx.x, smem);
}
__launch_bounds__(512) __global__ void k_f2(MegaP p) {
    __shared__ int smem[2048];
    int vb = blockIdx.x;
    if (vb < p.NB)
        csr_role(p, vb, threadIdx.x, smem);
    else
        gemm_body<128, true>(vb - p.NB, p.x, nullptr, p.WT1h, p.WT1l, p.Hbuf, p.als, p.ald,
                             p.N);
}
__launch_bounds__(512) __global__ void k_f3(MegaP p, const float* bias) {
    agg128_role(p, threadIdx.x, blockIdx.x, bias);
}
template <int M>
__launch_bounds__(512) __global__ void k_f4(MegaP p, const u16* Th, const u16* Tl) {
    gemm_body<M, false>(blockIdx.x, nullptr, p.XH, Th, Tl, p.Hbuf, p.als, p.ald, p.N);
}
__launch_bounds__(512) __global__ void k_f7(MegaP p) {
    agg64_role(p, threadIdx.x, blockIdx.x);
}

// ---------------- launch ----------------

extern "C" void kernel_launch(void* const* d_in, const int* in_sizes, int n_in,
                              void* d_out, int out_size, void* d_ws, size_t ws_size,
                              hipStream_t stream) {
    MegaP P;
    P.x = (const float*)d_in[0];
    P.ei = (const int*)d_in[1];
    P.W1 = (const float*)d_in[2];
    P.as1 = (const float*)d_in[3];
    P.ad1 = (const float*)d_in[4];
    P.b1 = (const float*)d_in[5];
    P.W2 = (const float*)d_in[6];
    P.as2 = (const float*)d_in[7];
    P.ad2 = (const float*)d_in[8];
    P.b2 = (const float*)d_in[9];
    P.W3 = (const float*)d_in[10];
    P.as3 = (const float*)d_in[11];
    P.ad3 = (const float*)d_in[12];
    P.b3 = (const float*)d_in[13];
    P.out = (float*)d_out;

    const int N = in_sizes[0] / 128;
    const int E = in_sizes[1] / 2;
    P.N = N;
    P.E = E;
    P.NB = (N + BUK_SIZE - 1) / BUK_SIZE;
    P.NBIN = (E + 4095) / 4096;
    const int Npad = (N + 255) & ~255;
    P.GTOT = Npad / 256;
    P.VB128 = ((N + 3) / 4 + 7) / 8;
    P.VB64 = ((N + 7) / 8 + 7) / 8;

    char* p = (char*)d_ws;
    auto alloc = [&](size_t bytes) -> char* {
        char* r = p;
        p += (bytes + 255) & ~(size_t)255;
        return r;
    };
    P.g_cnt = (int*)alloc(256 * 4);
    P.buckets = (int*)alloc((size_t)P.NB * BUK_CAP * 4);
    P.csr_ptr = (int*)alloc((size_t)(N + 1) * 4);
    P.csr_src = (int*)alloc((size_t)(E + N) * 4);
    P.als = (float*)alloc((size_t)N * 2 * 4);
    P.ald = (float*)alloc((size_t)N * 2 * 4);
    P.Hbuf = (_Float16*)alloc((size_t)N * 128 * 2);
    P.XH = (u16*)alloc((size_t)Npad * 128 * 2);
    P.WT1h = (u16*)alloc(9 * 2048 * 2);
    P.WT1l = (u16*)alloc(9 * 2048 * 2);
    P.WT2h = (u16*)alloc(9 * 2048 * 2);
    P.WT2l = (u16*)alloc(9 * 2048 * 2);
    P.WT3h = (u16*)alloc(5 * 2048 * 2);
    P.WT3l = (u16*)alloc(5 * 2048 * 2);

    // one-time cooperative capacity query (host-side, capture-safe)
    static int nblk = -2;
    if (nblk == -2) {
        int mb = 0, dev = 0, ncu = 0;
        hipError_t e1 = hipGetDevice(&dev);
        hipError_t e2 = hipOccupancyMaxActiveBlocksPerMultiprocessor(&mb, mega, 512, 0);
        hipError_t e3 =
            hipDeviceGetAttribute(&ncu, hipDeviceAttributeMultiprocessorCount, dev);
        if (e1 == hipSuccess && e2 == hipSuccess && e3 == hipSuccess && mb > 0 && ncu > 0)
            nblk = mb * ncu;
        else
            nblk = 0;
    }

    bool done = false;
    if (nblk > 0) {
        int g = nblk < P.VB128 ? nblk : P.VB128;
        void* args[] = {(void*)&P};
        if (hipLaunchCooperativeKernel((const void*)mega, dim3(g), dim3(512), args, 0,
                                       stream) == hipSuccess)
            done = true;
        else
            nblk = 0;  // stop trying; use fallback path from now on
    }
    if (!done) {
        k_f0<<<93, 512, 0, stream>>>(P);
        k_f1<<<P.NBIN, 512, 0, stream>>>(P);
        k_f2<<<P.NB + P.GTOT, 512, 0, stream>>>(P);
        k_f3<<<P.VB128, 512, 0, stream>>>(P, P.b1);
        k_f4<128><<<P.GTOT, 512, 0, stream>>>(P, P.WT2h, P.WT2l);
        k_f3<<<P.VB128, 512, 0, stream>>>(P, P.b2);
        k_f4<64><<<P.GTOT, 512, 0, stream>>>(P, P.WT3h, P.WT3l);
        k_f7<<<P.VB64, 512, 0, stream>>>(P);
    }
}

// Round 8
// 399.378 us; speedup vs baseline: 1.1123x; 1.1123x over previous
//
#include <hip/hip_runtime.h>

#define NEG_SLOPE 0.2f
#define BUK_SHIFT 9
#define BUK_SIZE 512
#define BUK_CAP 16384

typedef unsigned short u16;
typedef __attribute__((ext_vector_type(4))) float f4v;
typedef _Float16 h8 __attribute__((ext_vector_type(8)));  // 4 VGPRs, MFMA f16 A/B frag

__device__ __forceinline__ u16 f2h_bits(_Float16 h) {
    union { _Float16 f; u16 u; } c;
    c.f = h;
    return c.u;
}

// ---------------- GEMM body (f16 MFMA, fused logit columns), 512 thr / 256 rows ----------------
// B has CT+1 column-tiles; tile CT yields [als_h0, als_h1, ald_h0, ald_h1] per row.

__device__ __forceinline__ void load_split_f32(const float* __restrict__ X, int row,
                                               int koff, int N, h8& hi, h8& lo) {
    float v[8];
    if (row < N) {
        float4 a = *(const float4*)&X[(size_t)row * 128 + koff];
        float4 b = *(const float4*)&X[(size_t)row * 128 + koff + 4];
        v[0] = a.x; v[1] = a.y; v[2] = a.z; v[3] = a.w;
        v[4] = b.x; v[5] = b.y; v[6] = b.z; v[7] = b.w;
    } else {
#pragma unroll
        for (int i = 0; i < 8; i++) v[i] = 0.f;
    }
    union { h8 s; _Float16 u[8]; } H, L;
#pragma unroll
    for (int i = 0; i < 8; i++) {
        H.u[i] = (_Float16)v[i];
        L.u[i] = (_Float16)(v[i] - (float)H.u[i]);
    }
    hi = H.s;
    lo = L.s;
}

template <int M, bool FP32X>
__device__ __forceinline__ void gemm_body(int gb, const float* __restrict__ Xf,
                                          const u16* __restrict__ XH,
                                          const u16* __restrict__ WTh,
                                          const u16* __restrict__ WTl,
                                          _Float16* __restrict__ Hout,
                                          float* __restrict__ als,
                                          float* __restrict__ ald, int nrows) {
    const int CT = M / 16;
    const int CTX = CT + 1;
    const int H = (M == 128) ? 2 : 1;
    int tid = threadIdx.x;
    int wv = tid >> 6, lane = tid & 63;
    int q = lane >> 4, nl = lane & 15;
    int R0 = gb * 256 + wv * 32;
    int rt0 = R0 >> 4;

    f4v acc[2][CTX];
    f4v z4 = {0.f, 0.f, 0.f, 0.f};
#pragma unroll
    for (int rt = 0; rt < 2; rt++)
#pragma unroll
        for (int ct = 0; ct < CTX; ct++) acc[rt][ct] = z4;

#pragma unroll
    for (int ch = 0; ch < 4; ch++) {
        h8 ah0, al0, ah1, al1;
        if (FP32X) {
            int koff = ch * 32 + q * 8;
            load_split_f32(Xf, R0 + nl, koff, nrows, ah0, al0);
            load_split_f32(Xf, R0 + 16 + nl, koff, nrows, ah1, al1);
        } else {
            size_t a0 = ((size_t)rt0 * 4 + ch) * 512 + lane * 8;
            size_t a1 = ((size_t)(rt0 + 1) * 4 + ch) * 512 + lane * 8;
            ah0 = *(const h8*)&XH[a0];
            ah1 = *(const h8*)&XH[a1];
        }
#pragma unroll
        for (int ct = 0; ct < CTX; ct++) {
            size_t bb = ((size_t)ct * 4 + ch) * 512 + lane * 8;
            h8 bh = *(const h8*)&WTh[bb];
            h8 bl = *(const h8*)&WTl[bb];
            acc[0][ct] = __builtin_amdgcn_mfma_f32_16x16x32_f16(ah0, bh, acc[0][ct], 0, 0, 0);
            acc[0][ct] = __builtin_amdgcn_mfma_f32_16x16x32_f16(ah0, bl, acc[0][ct], 0, 0, 0);
            acc[1][ct] = __builtin_amdgcn_mfma_f32_16x16x32_f16(ah1, bh, acc[1][ct], 0, 0, 0);
            acc[1][ct] = __builtin_amdgcn_mfma_f32_16x16x32_f16(ah1, bl, acc[1][ct], 0, 0, 0);
            if (FP32X) {
                acc[0][ct] = __builtin_amdgcn_mfma_f32_16x16x32_f16(al0, bh, acc[0][ct], 0, 0, 0);
                acc[1][ct] = __builtin_amdgcn_mfma_f32_16x16x32_f16(al1, bh, acc[1][ct], 0, 0, 0);
            }
        }
    }

#pragma unroll
    for (int rt = 0; rt < 2; rt++)
#pragma unroll
        for (int ct = 0; ct < CT; ct++)
#pragma unroll
            for (int r = 0; r < 4; r++) {
                int row = R0 + rt * 16 + q * 4 + r;
                if (row < nrows) Hout[(size_t)row * M + ct * 16 + nl] = (_Float16)acc[rt][ct][r];
            }

    if (nl < 2 * H) {
#pragma unroll
        for (int rt = 0; rt < 2; rt++)
#pragma unroll
            for (int r = 0; r < 4; r++) {
                int row = R0 + rt * 16 + q * 4 + r;
                if (row < nrows) {
                    float v = acc[rt][CT][r];
                    if (H == 2) {
                        float* dstp = (nl < 2) ? als : ald;
                        dstp[(size_t)row * 2 + (nl & 1)] = v;
                    } else {
                        float* dstp = (nl == 0) ? als : ald;
                        dstp[row] = v;
                    }
                }
            }
    }
}

template <int M, bool FP32X>
__launch_bounds__(512)
__global__ void k_gemm(const float* __restrict__ Xf, const u16* __restrict__ XH,
                       const u16* __restrict__ WTh, const u16* __restrict__ WTl,
                       _Float16* __restrict__ Hout, float* __restrict__ als,
                       float* __restrict__ ald, int nrows) {
    gemm_body<M, FP32X>(blockIdx.x, Xf, XH, WTh, WTl, Hout, als, ald, nrows);
}

// ---------------- D1: binscatter(512thr) U wsplit U wa ----------------
// Roles by blockIdx; all roles mutually independent (cross-role data only crosses
// dispatch boundaries).

__launch_bounds__(512)
__global__ void k_d1(const int* __restrict__ ei, int* g_cnt, int* buckets, int E, int nb,
                     int nbin, const float* __restrict__ W1, const float* __restrict__ as1,
                     const float* __restrict__ ad1, const float* __restrict__ W2,
                     const float* __restrict__ as2, const float* __restrict__ ad2,
                     const float* __restrict__ W3, const float* __restrict__ as3,
                     const float* __restrict__ ad3, u16* __restrict__ T1h,
                     u16* __restrict__ T1l, u16* __restrict__ T2h, u16* __restrict__ T2l,
                     u16* __restrict__ T3h, u16* __restrict__ T3l) {
    __shared__ int lcnt[256], lbase[256], lcur[256];
    int b = blockIdx.x;
    int t = threadIdx.x;
    if (b < nbin) {
        // ---- binscatter role ----
        if (t < nb) {
            lcnt[t] = 0;
            lcur[t] = 0;
        }
        __syncthreads();
        int tile0 = b * 4096;
        int pk[8], bk[8];
#pragma unroll
        for (int k = 0; k < 8; k++) {
            int idx = tile0 + k * 512 + t;
            bk[k] = -1;
            if (idx < E) {
                int s = ei[idx];
                int d = ei[E + idx];
                bk[k] = d >> BUK_SHIFT;
                pk[k] = (s << BUK_SHIFT) | (d & (BUK_SIZE - 1));
                atomicAdd(&lcnt[bk[k]], 1);
            }
        }
        __syncthreads();
        if (t < nb && lcnt[t] > 0) lbase[t] = atomicAdd(&g_cnt[t], lcnt[t]);
        __syncthreads();
#pragma unroll
        for (int k = 0; k < 8; k++) {
            if (bk[k] >= 0) {
                int p = lbase[bk[k]] + atomicAdd(&lcur[bk[k]], 1);
                if (p < BUK_CAP) buckets[(bk[k] << 14) + p] = pk[k];
            }
        }
        return;
    }
    int rb = b - nbin;
    if (rb < 80) {
        // ---- wsplit role ----
        int idx = rb * 512 + t;  // 0..40959
        const float* W;
        u16 *Th, *Tl;
        int M, li;
        if (idx < 16384) {
            W = W1; Th = T1h; Tl = T1l; M = 128; li = idx;
        } else if (idx < 32768) {
            W = W2; Th = T2h; Tl = T2l; M = 128; li = idx - 16384;
        } else {
            W = W3; Th = T3h; Tl = T3l; M = 64; li = idx - 32768;
        }
        int c = li >> 7, k = li & 127;
        float v = W[(size_t)k * M + c];
        _Float16 h = (_Float16)v;
        _Float16 l = (_Float16)(v - (float)h);
        int ct = c >> 4, ch = k >> 5, q = (k >> 3) & 3, j = k & 7;
        size_t addr = ((size_t)ct * 4 + ch) * 512 + ((c & 15) + 16 * q) * 8 + j;
        Th[addr] = f2h_bits(h);
        Tl[addr] = f2h_bits(l);
    } else {
        // ---- wa role (logit columns, tile index CT) ----
        int idx = (rb - 80) * 512 + t;
        if (idx >= 6144) return;
        int layer = idx >> 11;
        int rem = idx & 2047;
        int k = rem >> 4;
        int c = rem & 15;
        const float *W, *as, *ad;
        u16 *Th, *Tl;
        int M, CT, nc;
        if (layer == 0) {
            W = W1; as = as1; ad = ad1; Th = T1h; Tl = T1l; M = 128; CT = 8; nc = 4;
        } else if (layer == 1) {
            W = W2; as = as2; ad = ad2; Th = T2h; Tl = T2l; M = 128; CT = 8; nc = 4;
        } else {
            W = W3; as = as3; ad = ad3; Th = T3h; Tl = T3l; M = 64; CT = 4; nc = 2;
        }
        float val = 0.f;
        if (c < nc) {
            int side, hh;
            if (nc == 4) { side = c >> 1; hh = c & 1; }
            else { side = c; hh = 0; }
            const float* a = side ? ad : as;
            for (int j = 0; j < 64; j++)
                val += W[(size_t)k * M + hh * 64 + j] * a[hh * 64 + j];
        }
        _Float16 h = (_Float16)val;
        _Float16 l = (_Float16)(val - (float)h);
        int ch = k >> 5, q = (k >> 3) & 3, j = k & 7;
        size_t addr = ((size_t)CT * 4 + ch) * 512 + ((size_t)(c + 16 * q)) * 8 + j;
        Th[addr] = f2h_bits(h);
        Tl[addr] = f2h_bits(l);
    }
}

// ---------------- D2: csr(512thr, unchanged body) U GEMM layer-1 ----------------
// csr needs binscatter (D1); gemm1 needs wsplit/wa tiles (D1). Mutually independent.

__launch_bounds__(512)
__global__ void k_d2(const int* __restrict__ g_cnt, const int* __restrict__ buckets,
                     int* csr_ptr, int* csr_src, int n, int nb,
                     const float* __restrict__ x, const u16* __restrict__ WTh,
                     const u16* __restrict__ WTl, _Float16* __restrict__ Hout,
                     float* __restrict__ als, float* __restrict__ ald) {
    __shared__ int lcnt[512], lsc[512], lcur[512], bsc[512];
    int b = blockIdx.x;
    int t = threadIdx.x;
    if (b >= nb) {
        gemm_body<128, true>(b - nb, x, nullptr, WTh, WTl, Hout, als, ald, n);
        return;
    }
    // ---- csr role ----
    int nodes = min(BUK_SIZE, n - b * BUK_SIZE);
    int cnt = min(g_cnt[b], BUK_CAP);
    const int* bp = &buckets[b << 14];

    int bv = 0;
    if (t < nb) bv = min(g_cnt[t], BUK_CAP) + min(BUK_SIZE, n - t * BUK_SIZE);
    bsc[t] = bv;
    __syncthreads();
    for (int off = 1; off < 512; off <<= 1) {
        int xx = (t >= off) ? bsc[t - off] : 0;
        __syncthreads();
        bsc[t] += xx;
        __syncthreads();
    }
    int boff = bsc[b] - (cnt + nodes);
    int total = bsc[nb - 1];
    __syncthreads();

    lcnt[t] = 0;
    __syncthreads();
    for (int i = t; i < cnt; i += 512) atomicAdd(&lcnt[bp[i] & (BUK_SIZE - 1)], 1);
    __syncthreads();
    int myc = (t < nodes) ? (lcnt[t] + 1) : 0;
    lsc[t] = myc;
    __syncthreads();
    for (int off = 1; off < 512; off <<= 1) {
        int xx = (t >= off) ? lsc[t - off] : 0;
        __syncthreads();
        lsc[t] += xx;
        __syncthreads();
    }
    int excl = lsc[t] - myc;
    lcur[t] = excl;
    if (t < nodes) csr_ptr[b * BUK_SIZE + t] = boff + excl;
    if (b == nb - 1 && t == 0) csr_ptr[n] = total;
    __syncthreads();
    for (int i = t; i < cnt; i += 512) {
        int v = bp[i];
        int ld = v & (BUK_SIZE - 1);
        int p = atomicAdd(&lcur[ld], 1);
        csr_src[boff + p] = v >> BUK_SHIFT;
    }
    if (t < nodes) {
        int p = atomicAdd(&lcur[t], 1);
        csr_src[boff + p] = b * BUK_SIZE + t;
    }
}

// ---------------- aggregation M=128: 4 nodes per wave, 16 lanes/node ----------------
// (round-3 form: at the random-gather service floor, ~75 us)

__launch_bounds__(256)
__global__ void k_agg128(const int* __restrict__ ptr, const int* __restrict__ srcv,
                         const _Float16* __restrict__ Hh, const float* __restrict__ als,
                         const float* __restrict__ ald, const float* __restrict__ bias,
                         u16* __restrict__ OutX, int n) {
    int wvg = (blockIdx.x * blockDim.x + threadIdx.x) >> 6;  // global wave id
    int lane = threadIdx.x & 63;
    int nn = lane >> 4;   // node slot 0..3
    int gl = lane & 15;   // lane within node: covers cols gl*8 .. gl*8+7
    int wid = wvg * 4 + nn;
    bool valid = wid < n;
    int widc = valid ? wid : (n - 1);
    int start = ptr[widc];
    int deg = valid ? (ptr[widc + 1] - start) : 0;
    int md = deg;
    md = max(md, __shfl_xor(md, 16));
    md = max(md, __shfl_xor(md, 32));
    float2 adv = *(const float2*)&ald[(size_t)widc * 2];
    int hsel = gl >> 3;  // cols < 64 -> head 0, else head 1
    int coff = gl * 8;
    float z0 = 0.f, z1 = 0.f;
    float acc[8];
#pragma unroll
    for (int c = 0; c < 8; c++) acc[c] = 0.f;

    for (int base = 0; base < md; base += 16) {
        int i = base + gl;
        int s_l = 0;
        float ex0 = 0.f, ex1 = 0.f;
        if (i < deg) {
            s_l = srcv[start + i];
            float2 av = *(const float2*)&als[(size_t)s_l * 2];
            float e0 = av.x + adv.x;
            e0 = e0 > 0.f ? e0 : NEG_SLOPE * e0;
            ex0 = __expf(e0);
            float e1 = av.y + adv.y;
            e1 = e1 > 0.f ? e1 : NEG_SLOPE * e1;
            ex1 = __expf(e1);
        }
        z0 += ex0;
        z1 += ex1;
        int cnt = min(16, md - base);  // wave-uniform
        for (int jp = 0; jp < cnt; jp += 4) {
            int nk = min(4, cnt - jp);  // wave-uniform
            h8 hv[4];
            float w[4];
#pragma unroll
            for (int k = 0; k < 4; k++) {
                if (k < nk) {
                    int j = nn * 16 + jp + k;
                    int s = __shfl(s_l, j);
                    float w0 = __shfl(ex0, j);
                    float w1 = __shfl(ex1, j);
                    w[k] = hsel ? w1 : w0;
                    hv[k] = *(const h8*)&Hh[(size_t)s * 128 + coff];
                }
            }
#pragma unroll
            for (int k = 0; k < 4; k++) {
                if (k < nk) {
#pragma unroll
                    for (int c = 0; c < 8; c++)
                        acc[c] = fmaf(w[k], (float)hv[k][c], acc[c]);
                }
            }
        }
    }

#pragma unroll
    for (int m = 1; m <= 8; m <<= 1) {
        z0 += __shfl_xor(z0, m);
        z1 += __shfl_xor(z1, m);
    }
    if (valid) {
        float zinv = hsel ? (1.f / z1) : (1.f / z0);
        float4 b0 = *(const float4*)&bias[coff];
        float4 b1 = *(const float4*)&bias[coff + 4];
        float bb[8] = {b0.x, b0.y, b0.z, b0.w, b1.x, b1.y, b1.z, b1.w};
        union { _Float16 f[8]; h8 v; } O;
#pragma unroll
        for (int c = 0; c < 8; c++) {
            float o = fmaxf(fmaf(acc[c], zinv, bb[c]), 0.f);
            O.f[c] = (_Float16)o;
        }
        int ch = coff >> 5, qq = (coff >> 3) & 3;
        size_t tb = ((size_t)(wid >> 4) * 4 + ch) * 512 + ((size_t)((wid & 15) + 16 * qq)) * 8;
        *(h8*)&OutX[tb] = O.v;
    }
}

// ---------------- aggregation M=64: 8 nodes per wave, 8 lanes/node ----------------

__launch_bounds__(256)
__global__ void k_agg64(const int* __restrict__ ptr, const int* __restrict__ srcv,
                        const _Float16* __restrict__ Hh, const float* __restrict__ als,
                        const float* __restrict__ ald, const float* __restrict__ bias,
                        float* __restrict__ Out, int n) {
    int wvg = (blockIdx.x * blockDim.x + threadIdx.x) >> 6;
    int lane = threadIdx.x & 63;
    int nn = lane >> 3;  // node slot 0..7
    int gl = lane & 7;   // covers cols gl*8 .. gl*8+7
    int wid = wvg * 8 + nn;
    bool valid = wid < n;
    int widc = valid ? wid : (n - 1);
    int start = ptr[widc];
    int deg = valid ? (ptr[widc + 1] - start) : 0;
    int md = deg;
    md = max(md, __shfl_xor(md, 8));
    md = max(md, __shfl_xor(md, 16));
    md = max(md, __shfl_xor(md, 32));
    float ad0 = ald[widc];
    int coff = gl * 8;
    float z = 0.f;
    float acc[8];
#pragma unroll
    for (int c = 0; c < 8; c++) acc[c] = 0.f;

    for (int base = 0; base < md; base += 8) {
        int i = base + gl;
        int s_l = 0;
        float ex0 = 0.f;
        if (i < deg) {
            s_l = srcv[start + i];
            float e = als[s_l] + ad0;
            e = e > 0.f ? e : NEG_SLOPE * e;
            ex0 = __expf(e);
        }
        z += ex0;
        int cnt = min(8, md - base);
        for (int jp = 0; jp < cnt; jp += 4) {
            int nk = min(4, cnt - jp);
            h8 hv[4];
            float w[4];
#pragma unroll
            for (int k = 0; k < 4; k++) {
                if (k < nk) {
                    int j = nn * 8 + jp + k;
                    int s = __shfl(s_l, j);
                    w[k] = __shfl(ex0, j);
                    hv[k] = *(const h8*)&Hh[(size_t)s * 64 + coff];
                }
            }
#pragma unroll
            for (int k = 0; k < 4; k++) {
                if (k < nk) {
#pragma unroll
                    for (int c = 0; c < 8; c++)
                        acc[c] = fmaf(w[k], (float)hv[k][c], acc[c]);
                }
            }
        }
    }

#pragma unroll
    for (int m = 1; m <= 4; m <<= 1) z += __shfl_xor(z, m);
    if (valid) {
        float zinv = 1.f / z;
        float4 b0 = *(const float4*)&bias[coff];
        float4 b1 = *(const float4*)&bias[coff + 4];
        float4 o1, o2;
        o1.x = fmaf(acc[0], zinv, b0.x);
        o1.y = fmaf(acc[1], zinv, b0.y);
        o1.z = fmaf(acc[2], zinv, b0.z);
        o1.w = fmaf(acc[3], zinv, b0.w);
        o2.x = fmaf(acc[4], zinv, b1.x);
        o2.y = fmaf(acc[5], zinv, b1.y);
        o2.z = fmaf(acc[6], zinv, b1.z);
        o2.w = fmaf(acc[7], zinv, b1.w);
        *(float4*)&Out[(size_t)wid * 64 + coff] = o1;
        *(float4*)&Out[(size_t)wid * 64 + coff + 4] = o2;
    }
}

// ---------------- launch ----------------

extern "C" void kernel_launch(void* const* d_in, const int* in_sizes, int n_in,
                              void* d_out, int out_size, void* d_ws, size_t ws_size,
                              hipStream_t stream) {
    const float* x = (const float*)d_in[0];
    const int* ei = (const int*)d_in[1];
    const float* W1 = (const float*)d_in[2];
    const float* as1 = (const float*)d_in[3];
    const float* ad1 = (const float*)d_in[4];
    const float* b1 = (const float*)d_in[5];
    const float* W2 = (const float*)d_in[6];
    const float* as2 = (const float*)d_in[7];
    const float* ad2 = (const float*)d_in[8];
    const float* b2 = (const float*)d_in[9];
    const float* W3 = (const float*)d_in[10];
    const float* as3 = (const float*)d_in[11];
    const float* ad3 = (const float*)d_in[12];
    const float* b3 = (const float*)d_in[13];

    const int N = in_sizes[0] / 128;
    const int E = in_sizes[1] / 2;
    const int NB = (N + BUK_SIZE - 1) / BUK_SIZE;
    const int Npad = (N + 255) & ~255;  // 256-row GEMM tiles

    char* p = (char*)d_ws;
    auto alloc = [&](size_t bytes) -> char* {
        char* r = p;
        p += (bytes + 255) & ~(size_t)255;
        return r;
    };
    int* g_cnt = (int*)alloc(256 * 4);
    int* buckets = (int*)alloc((size_t)NB * BUK_CAP * 4);
    int* csr_ptr = (int*)alloc((size_t)(N + 1) * 4);
    int* csr_src = (int*)alloc((size_t)(E + N) * 4);
    float* als = (float*)alloc((size_t)N * 2 * 4);
    float* aldv = (float*)alloc((size_t)N * 2 * 4);
    _Float16* Hbuf = (_Float16*)alloc((size_t)N * 128 * 2);
    u16* XH = (u16*)alloc((size_t)Npad * 128 * 2);
    // 9 column-tiles for M=128 layers, 5 for M=64 (tile CT = fused logit columns)
    u16* WT1h = (u16*)alloc(9 * 2048 * 2);
    u16* WT1l = (u16*)alloc(9 * 2048 * 2);
    u16* WT2h = (u16*)alloc(9 * 2048 * 2);
    u16* WT2l = (u16*)alloc(9 * 2048 * 2);
    u16* WT3h = (u16*)alloc(5 * 2048 * 2);
    u16* WT3l = (u16*)alloc(5 * 2048 * 2);

    const int GTOT = Npad / 256;                    // 512-thr GEMM blocks
    const int NBIN = (E + 4095) / 4096;             // binscatter blocks (512 thr x 8)
    const int waves128 = (N + 3) / 4;
    const int nbAgg128 = (waves128 + 3) / 4;        // 4 waves per 256-thr block
    const int waves64 = (N + 7) / 8;
    const int nbAgg64 = (waves64 + 3) / 4;

    // ---- g_cnt zero ----
    hipMemsetAsync(g_cnt, 0, 256 * 4, stream);

    // ---- D1: binscatter U wsplit U wa ----
    k_d1<<<NBIN + 92, 512, 0, stream>>>(ei, g_cnt, buckets, E, NB, NBIN,
                                        W1, as1, ad1, W2, as2, ad2, W3, as3, ad3,
                                        WT1h, WT1l, WT2h, WT2l, WT3h, WT3l);

    // ---- D2: csr U GEMM layer-1 ----
    k_d2<<<NB + GTOT, 512, 0, stream>>>(g_cnt, buckets, csr_ptr, csr_src, N, NB,
                                        x, WT1h, WT1l, Hbuf, als, aldv);

    k_agg128<<<nbAgg128, 256, 0, stream>>>(csr_ptr, csr_src, Hbuf, als, aldv, b1, XH, N);

    // ---- layer 2 (A = stored fp16, exact; 2 MFMAs) ----
    k_gemm<128, false><<<GTOT, 512, 0, stream>>>(nullptr, XH, WT2h, WT2l,
                                                 Hbuf, als, aldv, N);
    k_agg128<<<nbAgg128, 256, 0, stream>>>(csr_ptr, csr_src, Hbuf, als, aldv, b2, XH, N);

    // ---- layer 3 (M=64, mean==identity, no relu) ----
    k_gemm<64, false><<<GTOT, 512, 0, stream>>>(nullptr, XH, WT3h, WT3l,
                                                Hbuf, als, aldv, N);
    k_agg64<<<nbAgg64, 256, 0, stream>>>(csr_ptr, csr_src, Hbuf, als, aldv, b3,
                                         (float*)d_out, N);
}